// Round 5
// baseline (246.121 us; speedup 1.0000x reference)
//
#include <hip/hip_runtime.h>

// VQ-VAE VectorQuantizer fwd. K=1024, E=64, N=T*B=65536.
// Argmin tiers: bf16-split MFMA (gap<6e-6 flagged) -> fp64 exact re-resolve.
// Scores t = ||c||^2 - 2 x.c (row-constant ||x||^2 dropped); codebook
// pre-scaled by -2, ||c||^2 folded into MFMA C-init.
// MFMA roles: A = codebook fragment, B = x fragment, so D(lane l, reg r) =
// score(code = t*16 + (l>>4)*4 + r, row = base + (l&15)); C/D map per
// verified col=lane&15 (N), row=(lane>>4)*4+reg (M).
// R5: occupancy fix. argmin: 8-wave blocks, K-split per wave (8 tiles each),
// 64 rows/block, grid 1024, LDS cross-wave merge. output: 2048-block
// element-parallel. (R4 was 1 block/CU -> 9.8% occupancy, latency-bound.)

#define KC 1024
#define ED 64
#define NR 65536
#define NE (NR * ED)
#define GAP1 6e-6f

typedef __attribute__((ext_vector_type(8))) short short8;
typedef __attribute__((ext_vector_type(4))) float f32x4;

__device__ __forceinline__ unsigned short bf16rne(float f) {
    unsigned u = __builtin_bit_cast(unsigned, f);
    return (unsigned short)((u + 0x7fffu + ((u >> 16) & 1u)) >> 16);
}
__device__ __forceinline__ float bf16tof(unsigned short h) {
    return __builtin_bit_cast(float, (unsigned)h << 16);
}

// ee[k] = ||c_k||^2 (fp32) and e2d[k] (fp64)
__global__ __launch_bounds__(256) void k_prep_ee(const float* __restrict__ cb,
        float* __restrict__ ee, double* __restrict__ e2d) {
    int k = blockIdx.x * 256 + threadIdx.x;
    if (k >= KC) return;
    const float* c = cb + (size_t)k * ED;
    float s = 0.f; double sd = 0.0;
    for (int e = 0; e < ED; ++e) { float v = c[e]; s = fmaf(v, v, s); sd = fma((double)v, (double)v, sd); }
    ee[k] = s; e2d[k] = sd;
}

// Pack codebook fragments (MFMA A-operand): per code tile t, chunks j of
// -2*c: [ch e0-31|ch e32-63|cl e0-31|cl e32-63|ch e0-31|ch e32-63], paired
// at MFMA time with x chunks [xh0|xh1|xh0|xh1|xl0|xl1]. Element (g=l>>4,r)
// of a chunk <-> k-slot g*8+r (consistent bijection on both operands).
// cbp[(t*6+j)*64+l]; ee4p: reg r, lane l, tile t <-> code t*16+(l>>4)*4+r.
__global__ __launch_bounds__(256) void k_pack(const float* __restrict__ cb,
        const float* __restrict__ ee, short8* __restrict__ cbp,
        f32x4* __restrict__ ee4p) {
    int u = blockIdx.x * 256 + threadIdx.x;
    if (u < 64 * 6 * 64) {
        int t = u / 384, rem = u % 384, j = rem / 64, l = rem % 64;
        int code = t * 16 + (l & 15), g = l >> 4;
        const float* c = cb + (size_t)code * ED;
        short8 o;
#pragma unroll
        for (int r = 0; r < 8; ++r) {
            int k = j * 32 + g * 8 + r;
            int e; bool lo;
            if (j < 2)      { e = k;       lo = false; }
            else if (j < 4) { e = k - 64;  lo = true;  }
            else            { e = k - 128; lo = false; }
            float m2 = -2.f * c[e];
            unsigned short h = bf16rne(m2);
            o[r] = lo ? (short)bf16rne(m2 - bf16tof(h)) : (short)h;
        }
        cbp[u] = o;
    } else if (u < 64 * 6 * 64 + 64 * 64) {
        int v = u - 64 * 6 * 64;
        int t = v >> 6, l = v & 63, g = l >> 4;
        f32x4 o;
#pragma unroll
        for (int r = 0; r < 4; ++r) o[r] = ee[t * 16 + g * 4 + r];
        ee4p[v] = o;
    }
}

// 8 waves/block; block owns 64 rows (4 rowtiles x 16); wave w owns code
// tiles [w*8, w*8+8). Intra-wave g-merge via shfl, cross-wave merge in LDS
// (ascending w == ascending k ranges -> first-min tie-break preserved).
__global__ __launch_bounds__(512, 4) void k_argmin_mfma(
        const float* __restrict__ in, const short8* __restrict__ cbp,
        const f32x4* __restrict__ ee4p, int* __restrict__ idx,
        unsigned* __restrict__ flagcnt, unsigned* __restrict__ flaglist) {
    __shared__ float sb[8][4][16];
    __shared__ float sb2[8][4][16];
    __shared__ int   sk[8][4][16];

    const int tid = threadIdx.x;
    const int l = tid & 63;
    const int wid = tid >> 6;     // 0..7
    const int g = l >> 4;
    const int col = l & 15;
    const int rowBase = blockIdx.x * 64;

    short8 xh[4][2], xl[4][2];
#pragma unroll
    for (int rt = 0; rt < 4; ++rt) {
        const int row = rowBase + rt * 16 + col;
#pragma unroll
        for (int h = 0; h < 2; ++h) {
            short8 H, L;
#pragma unroll
            for (int r = 0; r < 8; ++r) {
                const int e = h * 32 + g * 8 + r;
                const float x = in[(size_t)e * NR + row];
                const unsigned short hb = bf16rne(x);
                H[r] = (short)hb;
                L[r] = (short)bf16rne(x - bf16tof(hb));
            }
            xh[rt][h] = H; xl[rt][h] = L;
        }
    }

    float best[4]  = {3.4e38f, 3.4e38f, 3.4e38f, 3.4e38f};
    float best2[4] = {3.4e38f, 3.4e38f, 3.4e38f, 3.4e38f};
    int bestk[4] = {0, 0, 0, 0};

    const int t0 = wid * 8;
#pragma unroll 2
    for (int tt = 0; tt < 8; ++tt) {
        const int t = t0 + tt;
        const short8* bp = cbp + t * 384 + l;
        const short8 b0 = bp[0], b1 = bp[64], b2 = bp[128],
                     b3 = bp[192], b4 = bp[256], b5 = bp[320];
        const f32x4 e4 = ee4p[t * 64 + l];
#pragma unroll
        for (int rt = 0; rt < 4; ++rt) {
            f32x4 acc = e4;
            acc = __builtin_amdgcn_mfma_f32_16x16x32_bf16(b0, xh[rt][0], acc, 0, 0, 0);
            acc = __builtin_amdgcn_mfma_f32_16x16x32_bf16(b1, xh[rt][1], acc, 0, 0, 0);
            acc = __builtin_amdgcn_mfma_f32_16x16x32_bf16(b2, xh[rt][0], acc, 0, 0, 0);
            acc = __builtin_amdgcn_mfma_f32_16x16x32_bf16(b3, xh[rt][1], acc, 0, 0, 0);
            acc = __builtin_amdgcn_mfma_f32_16x16x32_bf16(b4, xl[rt][0], acc, 0, 0, 0);
            acc = __builtin_amdgcn_mfma_f32_16x16x32_bf16(b5, xl[rt][1], acc, 0, 0, 0);
#pragma unroll
            for (int r = 0; r < 4; ++r) {
                const float v = acc[r];
                const int k = t * 16 + g * 4 + r;
                const bool c = v < best[rt];
                best2[rt] = c ? best[rt] : fminf(best2[rt], v);
                bestk[rt] = c ? k : bestk[rt];
                best[rt]  = c ? v : best[rt];
            }
        }
    }

#pragma unroll
    for (int rt = 0; rt < 4; ++rt) {
        float b = best[rt], b2 = best2[rt]; int k = bestk[rt];
#pragma unroll
        for (int sh = 16; sh <= 32; sh <<= 1) {    // merge the 4 g-groups
            const float ob  = __shfl_xor(b, sh, 64);
            const float ob2 = __shfl_xor(b2, sh, 64);
            const int   ok  = __shfl_xor(k, sh, 64);
            if (ob < b || (ob == b && ok < k)) { b2 = fminf(b, ob2); k = ok; b = ob; }
            else b2 = fminf(b2, ob);
        }
        if (g == 0) { sb[wid][rt][col] = b; sb2[wid][rt][col] = b2; sk[wid][rt][col] = k; }
    }
    __syncthreads();

    if (wid == 0) {                                 // lane l -> (rt=l>>4, col=l&15)
        const int rt = l >> 4, c2 = l & 15;
        float b = sb[0][rt][c2], b2 = sb2[0][rt][c2]; int k = sk[0][rt][c2];
#pragma unroll
        for (int w = 1; w < 8; ++w) {               // ascending k ranges
            const float ob = sb[w][rt][c2], ob2 = sb2[w][rt][c2];
            const int ok = sk[w][rt][c2];
            if (ob < b || (ob == b && ok < k)) { b2 = fminf(b, ob2); k = ok; b = ob; }
            else b2 = fminf(b2, ob);
        }
        const int row = rowBase + rt * 16 + c2;
        idx[row] = k;
        if (b2 - b < GAP1) {
            const unsigned p = atomicAdd(flagcnt, 1u);
            flaglist[p] = (unsigned)row;
        }
    }
}

// fp64 exact argmin for flagged rows; one wave per row.
__global__ __launch_bounds__(256) void k_exact64(
        const float* __restrict__ in, const float* __restrict__ cb,
        const double* __restrict__ e2d, int* __restrict__ idx,
        const unsigned* __restrict__ flagcnt, const unsigned* __restrict__ flaglist) {
    const unsigned nf = *flagcnt;
    const int l = threadIdx.x & 63;
    const unsigned wave = blockIdx.x * 4u + (unsigned)(threadIdx.x >> 6);
    const unsigned nwave = gridDim.x * 4u;
    for (unsigned i = wave; i < nf; i += nwave) {
        const int row = (int)flaglist[i];
        float x[ED];
#pragma unroll
        for (int e = 0; e < ED; ++e) x[e] = in[(size_t)e * NR + row];
        double best = 1e300; int bestk = 0;
        for (int ci = 0; ci < 16; ++ci) {
            const int k = ci * 64 + l;              // ascending k per lane
            const float* c = cb + (size_t)k * ED;
            double s = 0.0;
            for (int e = 0; e < ED; ++e) s = fma((double)c[e], (double)x[e], s);
            const double t = fma(-2.0, s, e2d[k]);
            if (t < best) { best = t; bestk = k; }
        }
        for (int sh = 1; sh < 64; sh <<= 1) {
            const double ob = __shfl_xor(best, sh, 64);
            const int   ok  = __shfl_xor(bestk, sh, 64);
            if (ob < best || (ob == best && ok < bestk)) { best = ob; bestk = ok; }
        }
        if (l == 0) idx[row] = bestk;
    }
}

// Element-parallel gather/write/SSE + histogram (e0==0 lane per row).
// gtid in [0, 524288): n = gtid & 65535, e-range = [ (gtid>>16)*8, +8 ).
__global__ __launch_bounds__(256) void k_output(
        const float* __restrict__ in, const float* __restrict__ cb,
        const int* __restrict__ idx, float* __restrict__ qout,
        unsigned* __restrict__ counts, double* __restrict__ sse) {
    const int gtid = blockIdx.x * 256 + threadIdx.x;
    const int n = gtid & (NR - 1);
    const int e0 = gtid >> 16;                      // 0..7
    const int k = idx[n];
    if (e0 == 0) atomicAdd(&counts[k], 1u);
    const float* c = cb + (size_t)k * ED;
    float local = 0.f;
#pragma unroll
    for (int j = 0; j < 8; ++j) {
        const int e = e0 * 8 + j;
        const float q  = c[e];
        const float xv = in[(size_t)e * NR + n];
        qout[(size_t)e * NR + n] = q;
        const float d = q - xv;
        local = fmaf(d, d, local);
    }
    double ld = (double)local;
#pragma unroll
    for (int off = 32; off > 0; off >>= 1) ld += __shfl_down(ld, off, 64);
    if ((threadIdx.x & 63) == 0) atomicAdd(sse, ld);
}

__global__ __launch_bounds__(1024) void k_final(const unsigned* __restrict__ counts,
        const double* __restrict__ sse, float* __restrict__ out) {
    __shared__ double red[16];
    const int tid = threadIdx.x;
    const double p = (double)counts[tid] * (1.0 / 65536.0);
    double term = p * log(p + 1e-10);
#pragma unroll
    for (int off = 32; off > 0; off >>= 1) term += __shfl_down(term, off, 64);
    if ((tid & 63) == 0) red[tid >> 6] = term;
    __syncthreads();
    if (tid == 0) {
        double s = 0.0;
        for (int i = 0; i < 16; ++i) s += red[i];
        out[1 + NE] = (float)exp(-s);                 // perplexity
        const double m = *sse * (1.0 / 4194304.0);    // mean((q-x)^2)
        out[0] = (float)(1.25 * m);                   // (1+beta)*m
    }
}

extern "C" void kernel_launch(void* const* d_in, const int* in_sizes, int n_in,
                              void* d_out, int out_size, void* d_ws, size_t ws_size,
                              hipStream_t stream) {
    (void)in_sizes; (void)n_in; (void)out_size; (void)ws_size;
    const float* in = (const float*)d_in[0];
    const float* cb = (const float*)d_in[1];
    float* out = (float*)d_out;

    // ws layout (dword offsets), strictly disjoint:
    //  [0,1024) counts | [1024] flagcnt | [1026,1028) sse (byte 4104)
    //  [1088,2112) ee | [2112,4160) e2d (byte 8448)
    //  [4160,102464) cbp 24576 short8 | [102464,118848) ee4p 4096 f32x4
    //  [118848,184384) idx | [184384,249920) flaglist
    unsigned* counts   = (unsigned*)d_ws;
    unsigned* flagcnt  = (unsigned*)d_ws + 1024;
    double*   sse      = (double*)((char*)d_ws + 4104);
    float*    ee       = (float*)d_ws + 1088;
    double*   e2d      = (double*)((char*)d_ws + 8448);
    short8*   cbp      = (short8*)((float*)d_ws + 4160);
    f32x4*    ee4p     = (f32x4*)((float*)d_ws + 102464);
    int*      idx      = (int*)d_ws + 118848;
    unsigned* flaglist = (unsigned*)d_ws + 184384;

    hipMemsetAsync(d_ws, 0, 4112, stream);  // counts + flagcnt + sse

    hipLaunchKernelGGL(k_prep_ee,    dim3(4),    dim3(256), 0, stream, cb, ee, e2d);
    hipLaunchKernelGGL(k_pack,       dim3(112),  dim3(256), 0, stream, cb, ee, cbp, ee4p);
    hipLaunchKernelGGL(k_argmin_mfma,dim3(1024), dim3(512), 0, stream,
                       in, cbp, ee4p, idx, flagcnt, flaglist);
    hipLaunchKernelGGL(k_exact64,    dim3(128),  dim3(256), 0, stream,
                       in, cb, e2d, idx, flagcnt, flaglist);
    hipLaunchKernelGGL(k_output,     dim3(2048), dim3(256), 0, stream,
                       in, cb, idx, out + 1, counts, sse);
    hipLaunchKernelGGL(k_final,      dim3(1),    dim3(1024), 0, stream,
                       counts, sse, out);
}

// Round 6
// 220.995 us; speedup vs baseline: 1.1137x; 1.1137x over previous
//
#include <hip/hip_runtime.h>

// VQ-VAE VectorQuantizer fwd. K=1024, E=64, N=T*B=65536.
// bf16-split MFMA argmin (gap<6e-6 flagged) -> fp64 exact re-resolve.
// Scores t = ||c||^2 - 2 x.c; codebook pre-scaled by -2, ||c||^2 in C-init.
// MFMA roles: A = codebook frag, B = x frag -> D(lane l, reg r) =
// score(code = t*16 + (l>>4)*4 + r, row = base + (l&15)).
// R6: occupancy via grid K-split (4 splits x 256 row-groups = 1024 blocks,
// 4 waves each, 64 rows/wave, 16 codetiles/block) + partial top-2 merge
// kernel. launch_bounds(256,4) caps VGPR at 128 >= ~88 live set (R5's
// (512,4) capped at 64 -> massive scratch spill, WRITE_SIZE 204MB).

#define KC 1024
#define ED 64
#define NR 65536
#define NE (NR * ED)
#define GAP1 6e-6f

typedef __attribute__((ext_vector_type(8))) short short8;
typedef __attribute__((ext_vector_type(4))) float f32x4;

__device__ __forceinline__ unsigned short bf16rne(float f) {
    unsigned u = __builtin_bit_cast(unsigned, f);
    return (unsigned short)((u + 0x7fffu + ((u >> 16) & 1u)) >> 16);
}
__device__ __forceinline__ float bf16tof(unsigned short h) {
    return __builtin_bit_cast(float, (unsigned)h << 16);
}

// ee[k] = ||c_k||^2 (fp32) and e2d[k] (fp64)
__global__ __launch_bounds__(256) void k_prep_ee(const float* __restrict__ cb,
        float* __restrict__ ee, double* __restrict__ e2d) {
    int k = blockIdx.x * 256 + threadIdx.x;
    if (k >= KC) return;
    const float* c = cb + (size_t)k * ED;
    float s = 0.f; double sd = 0.0;
    for (int e = 0; e < ED; ++e) { float v = c[e]; s = fmaf(v, v, s); sd = fma((double)v, (double)v, sd); }
    ee[k] = s; e2d[k] = sd;
}

// Pack codebook fragments (MFMA A-operand): per code tile t, chunks j of
// -2*c: [ch e0-31|ch e32-63|cl e0-31|cl e32-63|ch e0-31|ch e32-63], paired
// at MFMA time with x chunks [xh0|xh1|xh0|xh1|xl0|xl1]. Element (g=l>>4,r)
// of a chunk <-> k-slot g*8+r (same bijection on both operands).
// cbp[(t*6+j)*64+l]; ee4p: reg r, lane l, tile t <-> code t*16+(l>>4)*4+r.
__global__ __launch_bounds__(256) void k_pack(const float* __restrict__ cb,
        const float* __restrict__ ee, short8* __restrict__ cbp,
        f32x4* __restrict__ ee4p) {
    int u = blockIdx.x * 256 + threadIdx.x;
    if (u < 64 * 6 * 64) {
        int t = u / 384, rem = u % 384, j = rem / 64, l = rem % 64;
        int code = t * 16 + (l & 15), g = l >> 4;
        const float* c = cb + (size_t)code * ED;
        short8 o;
#pragma unroll
        for (int r = 0; r < 8; ++r) {
            int k = j * 32 + g * 8 + r;
            int e; bool lo;
            if (j < 2)      { e = k;       lo = false; }
            else if (j < 4) { e = k - 64;  lo = true;  }
            else            { e = k - 128; lo = false; }
            float m2 = -2.f * c[e];
            unsigned short h = bf16rne(m2);
            o[r] = lo ? (short)bf16rne(m2 - bf16tof(h)) : (short)h;
        }
        cbp[u] = o;
    } else if (u < 64 * 6 * 64 + 64 * 64) {
        int v = u - 64 * 6 * 64;
        int t = v >> 6, l = v & 63, g = l >> 4;
        f32x4 o;
#pragma unroll
        for (int r = 0; r < 4; ++r) o[r] = ee[t * 16 + g * 4 + r];
        ee4p[v] = o;
    }
}

// grid = 256 row-groups x 4 K-splits. Block: 4 waves, wave owns 64 rows
// (4 rowtiles x 16), scans codetiles [ks*16, ks*16+16). Partial top-2 per
// row per split written to pb/pb2/pk at row*4+ks (ks asc == k asc).
__global__ __launch_bounds__(256, 4) void k_argmin_part(
        const float* __restrict__ in, const short8* __restrict__ cbp,
        const f32x4* __restrict__ ee4p, float* __restrict__ pb,
        float* __restrict__ pb2, int* __restrict__ pk) {
    const int tid = threadIdx.x;
    const int l = tid & 63;
    const int wid = tid >> 6;
    const int g = l >> 4;
    const int col = l & 15;
    const int ks = blockIdx.x & 3;
    const int rowBase = (blockIdx.x >> 2) * 256 + wid * 64;

    short8 xh[4][2], xl[4][2];
#pragma unroll
    for (int rt = 0; rt < 4; ++rt) {
        const int row = rowBase + rt * 16 + col;
#pragma unroll
        for (int h = 0; h < 2; ++h) {
            short8 H, L;
#pragma unroll
            for (int r = 0; r < 8; ++r) {
                const int e = h * 32 + g * 8 + r;
                const float x = in[(size_t)e * NR + row];
                const unsigned short hb = bf16rne(x);
                H[r] = (short)hb;
                L[r] = (short)bf16rne(x - bf16tof(hb));
            }
            xh[rt][h] = H; xl[rt][h] = L;
        }
    }

    float best[4]  = {3.4e38f, 3.4e38f, 3.4e38f, 3.4e38f};
    float best2[4] = {3.4e38f, 3.4e38f, 3.4e38f, 3.4e38f};
    int bestk[4] = {0, 0, 0, 0};

    const int t0 = ks * 16;
#pragma unroll 2
    for (int tt = 0; tt < 16; ++tt) {
        const int t = t0 + tt;
        const short8* bp = cbp + t * 384 + l;
        const short8 b0 = bp[0], b1 = bp[64], b2 = bp[128],
                     b3 = bp[192], b4 = bp[256], b5 = bp[320];
        const f32x4 e4 = ee4p[t * 64 + l];
#pragma unroll
        for (int rt = 0; rt < 4; ++rt) {
            f32x4 acc = e4;
            acc = __builtin_amdgcn_mfma_f32_16x16x32_bf16(b0, xh[rt][0], acc, 0, 0, 0);
            acc = __builtin_amdgcn_mfma_f32_16x16x32_bf16(b1, xh[rt][1], acc, 0, 0, 0);
            acc = __builtin_amdgcn_mfma_f32_16x16x32_bf16(b2, xh[rt][0], acc, 0, 0, 0);
            acc = __builtin_amdgcn_mfma_f32_16x16x32_bf16(b3, xh[rt][1], acc, 0, 0, 0);
            acc = __builtin_amdgcn_mfma_f32_16x16x32_bf16(b4, xl[rt][0], acc, 0, 0, 0);
            acc = __builtin_amdgcn_mfma_f32_16x16x32_bf16(b5, xl[rt][1], acc, 0, 0, 0);
#pragma unroll
            for (int r = 0; r < 4; ++r) {
                const float v = acc[r];
                const int k = t * 16 + g * 4 + r;
                const bool c = v < best[rt];
                best2[rt] = c ? best[rt] : fminf(best2[rt], v);
                bestk[rt] = c ? k : bestk[rt];
                best[rt]  = c ? v : best[rt];
            }
        }
    }

#pragma unroll
    for (int rt = 0; rt < 4; ++rt) {
        float b = best[rt], b2 = best2[rt]; int k = bestk[rt];
#pragma unroll
        for (int sh = 16; sh <= 32; sh <<= 1) {    // merge the 4 g-groups
            const float ob  = __shfl_xor(b, sh, 64);
            const float ob2 = __shfl_xor(b2, sh, 64);
            const int   ok  = __shfl_xor(k, sh, 64);
            if (ob < b || (ob == b && ok < k)) { b2 = fminf(b, ob2); k = ok; b = ob; }
            else b2 = fminf(b2, ob);
        }
        if (g == 0) {
            const int row = rowBase + rt * 16 + col;
            pb[row * 4 + ks] = b; pb2[row * 4 + ks] = b2; pk[row * 4 + ks] = k;
        }
    }
}

// Merge the 4 K-split partials per row; write idx; flag small-gap rows.
__global__ __launch_bounds__(256) void k_merge(
        const float* __restrict__ pb, const float* __restrict__ pb2,
        const int* __restrict__ pk, int* __restrict__ idx,
        unsigned* __restrict__ flagcnt, unsigned* __restrict__ flaglist) {
    const int n = blockIdx.x * 256 + threadIdx.x;
    float b = pb[n * 4], b2 = pb2[n * 4]; int k = pk[n * 4];
#pragma unroll
    for (int s = 1; s < 4; ++s) {                   // ascending k ranges
        const float ob = pb[n * 4 + s], ob2 = pb2[n * 4 + s];
        const int ok = pk[n * 4 + s];
        if (ob < b || (ob == b && ok < k)) { b2 = fminf(b, ob2); k = ok; b = ob; }
        else b2 = fminf(b2, ob);
    }
    idx[n] = k;
    if (b2 - b < GAP1) {
        const unsigned p = atomicAdd(flagcnt, 1u);
        flaglist[p] = (unsigned)n;
    }
}

// fp64 exact argmin for flagged rows; one wave per row.
__global__ __launch_bounds__(256) void k_exact64(
        const float* __restrict__ in, const float* __restrict__ cb,
        const double* __restrict__ e2d, int* __restrict__ idx,
        const unsigned* __restrict__ flagcnt, const unsigned* __restrict__ flaglist) {
    const unsigned nf = *flagcnt;
    const int l = threadIdx.x & 63;
    const unsigned wave = blockIdx.x * 4u + (unsigned)(threadIdx.x >> 6);
    const unsigned nwave = gridDim.x * 4u;
    for (unsigned i = wave; i < nf; i += nwave) {
        const int row = (int)flaglist[i];
        float x[ED];
#pragma unroll
        for (int e = 0; e < ED; ++e) x[e] = in[(size_t)e * NR + row];
        double best = 1e300; int bestk = 0;
        for (int ci = 0; ci < 16; ++ci) {
            const int k = ci * 64 + l;              // ascending k per lane
            const float* c = cb + (size_t)k * ED;
            double s = 0.0;
            for (int e = 0; e < ED; ++e) s = fma((double)c[e], (double)x[e], s);
            const double t = fma(-2.0, s, e2d[k]);
            if (t < best) { best = t; bestk = k; }
        }
        for (int sh = 1; sh < 64; sh <<= 1) {
            const double ob = __shfl_xor(best, sh, 64);
            const int   ok  = __shfl_xor(bestk, sh, 64);
            if (ob < best || (ob == best && ok < bestk)) { best = ob; bestk = ok; }
        }
        if (l == 0) idx[row] = bestk;
    }
}

// Element-parallel gather/write/SSE + histogram (e0==0 thread per row).
__global__ __launch_bounds__(256) void k_output(
        const float* __restrict__ in, const float* __restrict__ cb,
        const int* __restrict__ idx, float* __restrict__ qout,
        unsigned* __restrict__ counts, double* __restrict__ sse) {
    const int gtid = blockIdx.x * 256 + threadIdx.x;
    const int n = gtid & (NR - 1);
    const int e0 = gtid >> 16;                      // 0..7
    const int k = idx[n];
    if (e0 == 0) atomicAdd(&counts[k], 1u);
    const float* c = cb + (size_t)k * ED;
    float local = 0.f;
#pragma unroll
    for (int j = 0; j < 8; ++j) {
        const int e = e0 * 8 + j;
        const float q  = c[e];
        const float xv = in[(size_t)e * NR + n];
        qout[(size_t)e * NR + n] = q;
        const float d = q - xv;
        local = fmaf(d, d, local);
    }
    double ld = (double)local;
#pragma unroll
    for (int off = 32; off > 0; off >>= 1) ld += __shfl_down(ld, off, 64);
    if ((threadIdx.x & 63) == 0) atomicAdd(sse, ld);
}

__global__ __launch_bounds__(1024) void k_final(const unsigned* __restrict__ counts,
        const double* __restrict__ sse, float* __restrict__ out) {
    __shared__ double red[16];
    const int tid = threadIdx.x;
    const double p = (double)counts[tid] * (1.0 / 65536.0);
    double term = p * log(p + 1e-10);
#pragma unroll
    for (int off = 32; off > 0; off >>= 1) term += __shfl_down(term, off, 64);
    if ((tid & 63) == 0) red[tid >> 6] = term;
    __syncthreads();
    if (tid == 0) {
        double s = 0.0;
        for (int i = 0; i < 16; ++i) s += red[i];
        out[1 + NE] = (float)exp(-s);                 // perplexity
        const double m = *sse * (1.0 / 4194304.0);    // mean((q-x)^2)
        out[0] = (float)(1.25 * m);                   // (1+beta)*m
    }
}

extern "C" void kernel_launch(void* const* d_in, const int* in_sizes, int n_in,
                              void* d_out, int out_size, void* d_ws, size_t ws_size,
                              hipStream_t stream) {
    (void)in_sizes; (void)n_in; (void)out_size; (void)ws_size;
    const float* in = (const float*)d_in[0];
    const float* cb = (const float*)d_in[1];
    float* out = (float*)d_out;

    // ws layout (dword offsets), strictly disjoint:
    //  [0,1024) counts | [1024] flagcnt | [1026,1028) sse (byte 4104)
    //  [1088,2112) ee | [2112,4160) e2d | [4160,102464) cbp 24576 short8
    //  [102464,118848) ee4p | [118848,184384) idx | [184384,249920) flaglist
    //  [249920,512064) pb | [512064,774208) pb2 | [774208,1036352) pk
    unsigned* counts   = (unsigned*)d_ws;
    unsigned* flagcnt  = (unsigned*)d_ws + 1024;
    double*   sse      = (double*)((char*)d_ws + 4104);
    float*    ee       = (float*)d_ws + 1088;
    double*   e2d      = (double*)((char*)d_ws + 8448);
    short8*   cbp      = (short8*)((float*)d_ws + 4160);
    f32x4*    ee4p     = (f32x4*)((float*)d_ws + 102464);
    int*      idx      = (int*)d_ws + 118848;
    unsigned* flaglist = (unsigned*)d_ws + 184384;
    float*    pb       = (float*)d_ws + 249920;
    float*    pb2      = (float*)d_ws + 512064;
    int*      pk       = (int*)d_ws + 774208;

    hipMemsetAsync(d_ws, 0, 4112, stream);  // counts + flagcnt + sse

    hipLaunchKernelGGL(k_prep_ee,     dim3(4),    dim3(256), 0, stream, cb, ee, e2d);
    hipLaunchKernelGGL(k_pack,        dim3(112),  dim3(256), 0, stream, cb, ee, cbp, ee4p);
    hipLaunchKernelGGL(k_argmin_part, dim3(1024), dim3(256), 0, stream,
                       in, cbp, ee4p, pb, pb2, pk);
    hipLaunchKernelGGL(k_merge,       dim3(256),  dim3(256), 0, stream,
                       pb, pb2, pk, idx, flagcnt, flaglist);
    hipLaunchKernelGGL(k_exact64,     dim3(128),  dim3(256), 0, stream,
                       in, cb, e2d, idx, flagcnt, flaglist);
    hipLaunchKernelGGL(k_output,      dim3(2048), dim3(256), 0, stream,
                       in, cb, idx, out + 1, counts, sse);
    hipLaunchKernelGGL(k_final,       dim3(1),    dim3(1024), 0, stream,
                       counts, sse, out);
}

// Round 7
// 131.936 us; speedup vs baseline: 1.8655x; 1.6750x over previous
//
#include <hip/hip_runtime.h>

// VQ-VAE VectorQuantizer fwd. K=1024, E=64, N=T*B=65536.
// bf16-split MFMA argmin (gap<6e-6 flagged) -> fp64 exact re-resolve.
// Scores t = ||c||^2 - 2 x.c; codebook pre-scaled by -2, ||c||^2 in C-init.
// MFMA roles: A = codebook frag, B = x frag -> D(lane l, reg r) =
// score(code = t*16 + (l>>4)*4 + r, row = base + (l&15)).
// R7: k_output's single-address fp64 atomicAdd (8192 waves serialized at one
// L2 channel -> 111us at 1.3% VALUBusy) replaced by per-block partials in
// ws + deterministic reduce in k_final. No other changes.

#define KC 1024
#define ED 64
#define NR 65536
#define NE (NR * ED)
#define GAP1 6e-6f

typedef __attribute__((ext_vector_type(8))) short short8;
typedef __attribute__((ext_vector_type(4))) float f32x4;

__device__ __forceinline__ unsigned short bf16rne(float f) {
    unsigned u = __builtin_bit_cast(unsigned, f);
    return (unsigned short)((u + 0x7fffu + ((u >> 16) & 1u)) >> 16);
}
__device__ __forceinline__ float bf16tof(unsigned short h) {
    return __builtin_bit_cast(float, (unsigned)h << 16);
}

// ee[k] = ||c_k||^2 (fp32) and e2d[k] (fp64)
__global__ __launch_bounds__(256) void k_prep_ee(const float* __restrict__ cb,
        float* __restrict__ ee, double* __restrict__ e2d) {
    int k = blockIdx.x * 256 + threadIdx.x;
    if (k >= KC) return;
    const float* c = cb + (size_t)k * ED;
    float s = 0.f; double sd = 0.0;
    for (int e = 0; e < ED; ++e) { float v = c[e]; s = fmaf(v, v, s); sd = fma((double)v, (double)v, sd); }
    ee[k] = s; e2d[k] = sd;
}

// Pack codebook fragments (MFMA A-operand): per code tile t, chunks j of
// -2*c: [ch e0-31|ch e32-63|cl e0-31|cl e32-63|ch e0-31|ch e32-63], paired
// at MFMA time with x chunks [xh0|xh1|xh0|xh1|xl0|xl1]. Element (g=l>>4,r)
// of a chunk <-> k-slot g*8+r (same bijection on both operands).
// cbp[(t*6+j)*64+l]; ee4p: reg r, lane l, tile t <-> code t*16+(l>>4)*4+r.
__global__ __launch_bounds__(256) void k_pack(const float* __restrict__ cb,
        const float* __restrict__ ee, short8* __restrict__ cbp,
        f32x4* __restrict__ ee4p) {
    int u = blockIdx.x * 256 + threadIdx.x;
    if (u < 64 * 6 * 64) {
        int t = u / 384, rem = u % 384, j = rem / 64, l = rem % 64;
        int code = t * 16 + (l & 15), g = l >> 4;
        const float* c = cb + (size_t)code * ED;
        short8 o;
#pragma unroll
        for (int r = 0; r < 8; ++r) {
            int k = j * 32 + g * 8 + r;
            int e; bool lo;
            if (j < 2)      { e = k;       lo = false; }
            else if (j < 4) { e = k - 64;  lo = true;  }
            else            { e = k - 128; lo = false; }
            float m2 = -2.f * c[e];
            unsigned short h = bf16rne(m2);
            o[r] = lo ? (short)bf16rne(m2 - bf16tof(h)) : (short)h;
        }
        cbp[u] = o;
    } else if (u < 64 * 6 * 64 + 64 * 64) {
        int v = u - 64 * 6 * 64;
        int t = v >> 6, l = v & 63, g = l >> 4;
        f32x4 o;
#pragma unroll
        for (int r = 0; r < 4; ++r) o[r] = ee[t * 16 + g * 4 + r];
        ee4p[v] = o;
    }
}

// grid = 256 row-groups x 4 K-splits. Block: 4 waves, wave owns 64 rows
// (4 rowtiles x 16), scans codetiles [ks*16, ks*16+16). Partial top-2 per
// row per split written to pb/pb2/pk at row*4+ks (ks asc == k asc).
__global__ __launch_bounds__(256, 4) void k_argmin_part(
        const float* __restrict__ in, const short8* __restrict__ cbp,
        const f32x4* __restrict__ ee4p, float* __restrict__ pb,
        float* __restrict__ pb2, int* __restrict__ pk) {
    const int tid = threadIdx.x;
    const int l = tid & 63;
    const int wid = tid >> 6;
    const int g = l >> 4;
    const int col = l & 15;
    const int ks = blockIdx.x & 3;
    const int rowBase = (blockIdx.x >> 2) * 256 + wid * 64;

    short8 xh[4][2], xl[4][2];
#pragma unroll
    for (int rt = 0; rt < 4; ++rt) {
        const int row = rowBase + rt * 16 + col;
#pragma unroll
        for (int h = 0; h < 2; ++h) {
            short8 H, L;
#pragma unroll
            for (int r = 0; r < 8; ++r) {
                const int e = h * 32 + g * 8 + r;
                const float x = in[(size_t)e * NR + row];
                const unsigned short hb = bf16rne(x);
                H[r] = (short)hb;
                L[r] = (short)bf16rne(x - bf16tof(hb));
            }
            xh[rt][h] = H; xl[rt][h] = L;
        }
    }

    float best[4]  = {3.4e38f, 3.4e38f, 3.4e38f, 3.4e38f};
    float best2[4] = {3.4e38f, 3.4e38f, 3.4e38f, 3.4e38f};
    int bestk[4] = {0, 0, 0, 0};

    const int t0 = ks * 16;
#pragma unroll 2
    for (int tt = 0; tt < 16; ++tt) {
        const int t = t0 + tt;
        const short8* bp = cbp + t * 384 + l;
        const short8 b0 = bp[0], b1 = bp[64], b2 = bp[128],
                     b3 = bp[192], b4 = bp[256], b5 = bp[320];
        const f32x4 e4 = ee4p[t * 64 + l];
#pragma unroll
        for (int rt = 0; rt < 4; ++rt) {
            f32x4 acc = e4;
            acc = __builtin_amdgcn_mfma_f32_16x16x32_bf16(b0, xh[rt][0], acc, 0, 0, 0);
            acc = __builtin_amdgcn_mfma_f32_16x16x32_bf16(b1, xh[rt][1], acc, 0, 0, 0);
            acc = __builtin_amdgcn_mfma_f32_16x16x32_bf16(b2, xh[rt][0], acc, 0, 0, 0);
            acc = __builtin_amdgcn_mfma_f32_16x16x32_bf16(b3, xh[rt][1], acc, 0, 0, 0);
            acc = __builtin_amdgcn_mfma_f32_16x16x32_bf16(b4, xl[rt][0], acc, 0, 0, 0);
            acc = __builtin_amdgcn_mfma_f32_16x16x32_bf16(b5, xl[rt][1], acc, 0, 0, 0);
#pragma unroll
            for (int r = 0; r < 4; ++r) {
                const float v = acc[r];
                const int k = t * 16 + g * 4 + r;
                const bool c = v < best[rt];
                best2[rt] = c ? best[rt] : fminf(best2[rt], v);
                bestk[rt] = c ? k : bestk[rt];
                best[rt]  = c ? v : best[rt];
            }
        }
    }

#pragma unroll
    for (int rt = 0; rt < 4; ++rt) {
        float b = best[rt], b2 = best2[rt]; int k = bestk[rt];
#pragma unroll
        for (int sh = 16; sh <= 32; sh <<= 1) {    // merge the 4 g-groups
            const float ob  = __shfl_xor(b, sh, 64);
            const float ob2 = __shfl_xor(b2, sh, 64);
            const int   ok  = __shfl_xor(k, sh, 64);
            if (ob < b || (ob == b && ok < k)) { b2 = fminf(b, ob2); k = ok; b = ob; }
            else b2 = fminf(b2, ob);
        }
        if (g == 0) {
            const int row = rowBase + rt * 16 + col;
            pb[row * 4 + ks] = b; pb2[row * 4 + ks] = b2; pk[row * 4 + ks] = k;
        }
    }
}

// Merge the 4 K-split partials per row; write idx; flag small-gap rows.
__global__ __launch_bounds__(256) void k_merge(
        const float* __restrict__ pb, const float* __restrict__ pb2,
        const int* __restrict__ pk, int* __restrict__ idx,
        unsigned* __restrict__ flagcnt, unsigned* __restrict__ flaglist) {
    const int n = blockIdx.x * 256 + threadIdx.x;
    float b = pb[n * 4], b2 = pb2[n * 4]; int k = pk[n * 4];
#pragma unroll
    for (int s = 1; s < 4; ++s) {                   // ascending k ranges
        const float ob = pb[n * 4 + s], ob2 = pb2[n * 4 + s];
        const int ok = pk[n * 4 + s];
        if (ob < b || (ob == b && ok < k)) { b2 = fminf(b, ob2); k = ok; b = ob; }
        else b2 = fminf(b2, ob);
    }
    idx[n] = k;
    if (b2 - b < GAP1) {
        const unsigned p = atomicAdd(flagcnt, 1u);
        flaglist[p] = (unsigned)n;
    }
}

// fp64 exact argmin for flagged rows; one wave per row.
__global__ __launch_bounds__(256) void k_exact64(
        const float* __restrict__ in, const float* __restrict__ cb,
        const double* __restrict__ e2d, int* __restrict__ idx,
        const unsigned* __restrict__ flagcnt, const unsigned* __restrict__ flaglist) {
    const unsigned nf = *flagcnt;
    const int l = threadIdx.x & 63;
    const unsigned wave = blockIdx.x * 4u + (unsigned)(threadIdx.x >> 6);
    const unsigned nwave = gridDim.x * 4u;
    for (unsigned i = wave; i < nf; i += nwave) {
        const int row = (int)flaglist[i];
        float x[ED];
#pragma unroll
        for (int e = 0; e < ED; ++e) x[e] = in[(size_t)e * NR + row];
        double best = 1e300; int bestk = 0;
        for (int ci = 0; ci < 16; ++ci) {
            const int k = ci * 64 + l;              // ascending k per lane
            const float* c = cb + (size_t)k * ED;
            double s = 0.0;
            for (int e = 0; e < ED; ++e) s = fma((double)c[e], (double)x[e], s);
            const double t = fma(-2.0, s, e2d[k]);
            if (t < best) { best = t; bestk = k; }
        }
        for (int sh = 1; sh < 64; sh <<= 1) {
            const double ob = __shfl_xor(best, sh, 64);
            const int   ok  = __shfl_xor(bestk, sh, 64);
            if (ob < best || (ob == best && ok < bestk)) { best = ob; bestk = ok; }
        }
        if (l == 0) idx[row] = bestk;
    }
}

// Element-parallel gather/write/SSE + histogram. SSE: per-wave shfl reduce
// -> LDS -> one plain store per block (pblk[bid]); NO global atomics.
__global__ __launch_bounds__(256) void k_output(
        const float* __restrict__ in, const float* __restrict__ cb,
        const int* __restrict__ idx, float* __restrict__ qout,
        unsigned* __restrict__ counts, double* __restrict__ pblk) {
    __shared__ double sred[4];
    const int gtid = blockIdx.x * 256 + threadIdx.x;
    const int n = gtid & (NR - 1);
    const int e0 = gtid >> 16;                      // 0..7
    const int k = idx[n];
    if (e0 == 0) atomicAdd(&counts[k], 1u);
    const float4* c4 = (const float4*)(cb + (size_t)k * ED + e0 * 8);
    const float4 q0 = c4[0], q1 = c4[1];
    float local = 0.f;
#pragma unroll
    for (int j = 0; j < 8; ++j) {
        const int e = e0 * 8 + j;
        const float q = (j < 4) ? ((const float*)&q0)[j] : ((const float*)&q1)[j - 4];
        const float xv = in[(size_t)e * NR + n];
        qout[(size_t)e * NR + n] = q;
        const float d = q - xv;
        local = fmaf(d, d, local);
    }
    double ld = (double)local;
#pragma unroll
    for (int off = 32; off > 0; off >>= 1) ld += __shfl_down(ld, off, 64);
    if ((threadIdx.x & 63) == 0) sred[threadIdx.x >> 6] = ld;
    __syncthreads();
    if (threadIdx.x == 0)
        pblk[blockIdx.x] = (sred[0] + sred[1]) + (sred[2] + sred[3]);
}

// Final: entropy from counts + SSE from 2048 per-block partials (fixed-order
// tree -> deterministic).
__global__ __launch_bounds__(1024) void k_final(const unsigned* __restrict__ counts,
        const double* __restrict__ pblk, float* __restrict__ out) {
    __shared__ double redE[16], redS[16];
    const int tid = threadIdx.x;
    const double p = (double)counts[tid] * (1.0 / 65536.0);
    double term = p * log(p + 1e-10);
    double s = pblk[tid] + pblk[tid + 1024];
#pragma unroll
    for (int off = 32; off > 0; off >>= 1) {
        term += __shfl_down(term, off, 64);
        s    += __shfl_down(s,    off, 64);
    }
    if ((tid & 63) == 0) { redE[tid >> 6] = term; redS[tid >> 6] = s; }
    __syncthreads();
    if (tid == 0) {
        double e = 0.0, ss = 0.0;
        for (int i = 0; i < 16; ++i) { e += redE[i]; ss += redS[i]; }
        out[1 + NE] = (float)exp(-e);                 // perplexity
        const double m = ss * (1.0 / 4194304.0);      // mean((q-x)^2)
        out[0] = (float)(1.25 * m);                   // (1+beta)*m
    }
}

extern "C" void kernel_launch(void* const* d_in, const int* in_sizes, int n_in,
                              void* d_out, int out_size, void* d_ws, size_t ws_size,
                              hipStream_t stream) {
    (void)in_sizes; (void)n_in; (void)out_size; (void)ws_size;
    const float* in = (const float*)d_in[0];
    const float* cb = (const float*)d_in[1];
    float* out = (float*)d_out;

    // ws layout (dword offsets), strictly disjoint (lifetimes noted):
    //  [0,1024) counts | [1024] flagcnt | [1088,2112) ee | [2112,4160) e2d
    //  [4160,102464) cbp | [102464,118848) ee4p
    //  [118848,184384) idx | [184384,249920) flaglist
    //  [249920,512064) pb | [512064,774208) pb2 | [774208,1036352) pk
    //  pblk (2048 f64) OVERLAYS pb at dword 249920 (byte 999680, 8B-aligned):
    //  pb dead after k_merge; k_output writes pblk afterward (stream-ordered);
    //  both fully rewritten every call -> no cross-call state.
    unsigned* counts   = (unsigned*)d_ws;
    unsigned* flagcnt  = (unsigned*)d_ws + 1024;
    float*    ee       = (float*)d_ws + 1088;
    double*   e2d      = (double*)((char*)d_ws + 8448);
    short8*   cbp      = (short8*)((float*)d_ws + 4160);
    f32x4*    ee4p     = (f32x4*)((float*)d_ws + 102464);
    int*      idx      = (int*)d_ws + 118848;
    unsigned* flaglist = (unsigned*)d_ws + 184384;
    float*    pb       = (float*)d_ws + 249920;
    float*    pb2      = (float*)d_ws + 512064;
    int*      pk       = (int*)d_ws + 774208;
    double*   pblk     = (double*)((char*)d_ws + 999680);

    hipMemsetAsync(d_ws, 0, 4112, stream);  // counts + flagcnt

    hipLaunchKernelGGL(k_prep_ee,     dim3(4),    dim3(256), 0, stream, cb, ee, e2d);
    hipLaunchKernelGGL(k_pack,        dim3(112),  dim3(256), 0, stream, cb, ee, cbp, ee4p);
    hipLaunchKernelGGL(k_argmin_part, dim3(1024), dim3(256), 0, stream,
                       in, cbp, ee4p, pb, pb2, pk);
    hipLaunchKernelGGL(k_merge,       dim3(256),  dim3(256), 0, stream,
                       pb, pb2, pk, idx, flagcnt, flaglist);
    hipLaunchKernelGGL(k_exact64,     dim3(128),  dim3(256), 0, stream,
                       in, cb, e2d, idx, flagcnt, flaglist);
    hipLaunchKernelGGL(k_output,      dim3(2048), dim3(256), 0, stream,
                       in, cb, idx, out + 1, counts, pblk);
    hipLaunchKernelGGL(k_final,       dim3(1),    dim3(1024), 0, stream,
                       counts, pblk, out);
}

// Round 8
// 117.304 us; speedup vs baseline: 2.0981x; 1.1247x over previous
//
#include <hip/hip_runtime.h>

// VQ-VAE VectorQuantizer fwd. K=1024, E=64, N=T*B=65536.
// bf16-split MFMA argmin (gap<6e-6 flagged) -> fp64 exact re-resolve.
// Scores t = ||c||^2 - 2 x.c; codebook pre-scaled by -2, ||c||^2 in C-init.
// MFMA roles: A = codebook frag, B = x frag -> D(lane l, reg r) =
// score(code = t*16 + (l>>4)*4 + r, row = base + (l&15)).
// R8: __launch_bounds__(256,4) -> (256) on k_argmin_part. The 2nd arg
// forced a 64-VGPR budget (measured R5 AND R7) below the ~110-reg live set
// -> x-fragment spill (WRITE_SIZE 54MB vs 3.1MB of real output). Plain
// (256) measured 88 VGPR in R4's identical body; 16 waves x 88 <= 2048/CU
// so the 1024-block grid still gives 4 waves/SIMD.

#define KC 1024
#define ED 64
#define NR 65536
#define NE (NR * ED)
#define GAP1 6e-6f

typedef __attribute__((ext_vector_type(8))) short short8;
typedef __attribute__((ext_vector_type(4))) float f32x4;

__device__ __forceinline__ unsigned short bf16rne(float f) {
    unsigned u = __builtin_bit_cast(unsigned, f);
    return (unsigned short)((u + 0x7fffu + ((u >> 16) & 1u)) >> 16);
}
__device__ __forceinline__ float bf16tof(unsigned short h) {
    return __builtin_bit_cast(float, (unsigned)h << 16);
}

// ee[k] = ||c_k||^2 (fp32) and e2d[k] (fp64)
__global__ __launch_bounds__(256) void k_prep_ee(const float* __restrict__ cb,
        float* __restrict__ ee, double* __restrict__ e2d) {
    int k = blockIdx.x * 256 + threadIdx.x;
    if (k >= KC) return;
    const float* c = cb + (size_t)k * ED;
    float s = 0.f; double sd = 0.0;
    for (int e = 0; e < ED; ++e) { float v = c[e]; s = fmaf(v, v, s); sd = fma((double)v, (double)v, sd); }
    ee[k] = s; e2d[k] = sd;
}

// Pack codebook fragments (MFMA A-operand): per code tile t, chunks j of
// -2*c: [ch e0-31|ch e32-63|cl e0-31|cl e32-63|ch e0-31|ch e32-63], paired
// at MFMA time with x chunks [xh0|xh1|xh0|xh1|xl0|xl1]. Element (g=l>>4,r)
// of a chunk <-> k-slot g*8+r (same bijection on both operands).
// cbp[(t*6+j)*64+l]; ee4p: reg r, lane l, tile t <-> code t*16+(l>>4)*4+r.
__global__ __launch_bounds__(256) void k_pack(const float* __restrict__ cb,
        const float* __restrict__ ee, short8* __restrict__ cbp,
        f32x4* __restrict__ ee4p) {
    int u = blockIdx.x * 256 + threadIdx.x;
    if (u < 64 * 6 * 64) {
        int t = u / 384, rem = u % 384, j = rem / 64, l = rem % 64;
        int code = t * 16 + (l & 15), g = l >> 4;
        const float* c = cb + (size_t)code * ED;
        short8 o;
#pragma unroll
        for (int r = 0; r < 8; ++r) {
            int k = j * 32 + g * 8 + r;
            int e; bool lo;
            if (j < 2)      { e = k;       lo = false; }
            else if (j < 4) { e = k - 64;  lo = true;  }
            else            { e = k - 128; lo = false; }
            float m2 = -2.f * c[e];
            unsigned short h = bf16rne(m2);
            o[r] = lo ? (short)bf16rne(m2 - bf16tof(h)) : (short)h;
        }
        cbp[u] = o;
    } else if (u < 64 * 6 * 64 + 64 * 64) {
        int v = u - 64 * 6 * 64;
        int t = v >> 6, l = v & 63, g = l >> 4;
        f32x4 o;
#pragma unroll
        for (int r = 0; r < 4; ++r) o[r] = ee[t * 16 + g * 4 + r];
        ee4p[v] = o;
    }
}

// grid = 256 row-groups x 4 K-splits. Block: 4 waves, wave owns 64 rows
// (4 rowtiles x 16), scans codetiles [ks*16, ks*16+16). Partial top-2 per
// row per split written to pb/pb2/pk at row*4+ks (ks asc == k asc).
__global__ __launch_bounds__(256) void k_argmin_part(
        const float* __restrict__ in, const short8* __restrict__ cbp,
        const f32x4* __restrict__ ee4p, float* __restrict__ pb,
        float* __restrict__ pb2, int* __restrict__ pk) {
    const int tid = threadIdx.x;
    const int l = tid & 63;
    const int wid = tid >> 6;
    const int g = l >> 4;
    const int col = l & 15;
    const int ks = blockIdx.x & 3;
    const int rowBase = (blockIdx.x >> 2) * 256 + wid * 64;

    short8 xh[4][2], xl[4][2];
#pragma unroll
    for (int rt = 0; rt < 4; ++rt) {
        const int row = rowBase + rt * 16 + col;
#pragma unroll
        for (int h = 0; h < 2; ++h) {
            short8 H, L;
#pragma unroll
            for (int r = 0; r < 8; ++r) {
                const int e = h * 32 + g * 8 + r;
                const float x = in[(size_t)e * NR + row];
                const unsigned short hb = bf16rne(x);
                H[r] = (short)hb;
                L[r] = (short)bf16rne(x - bf16tof(hb));
            }
            xh[rt][h] = H; xl[rt][h] = L;
        }
    }

    float best[4]  = {3.4e38f, 3.4e38f, 3.4e38f, 3.4e38f};
    float best2[4] = {3.4e38f, 3.4e38f, 3.4e38f, 3.4e38f};
    int bestk[4] = {0, 0, 0, 0};

    const int t0 = ks * 16;
#pragma unroll 2
    for (int tt = 0; tt < 16; ++tt) {
        const int t = t0 + tt;
        const short8* bp = cbp + t * 384 + l;
        const short8 b0 = bp[0], b1 = bp[64], b2 = bp[128],
                     b3 = bp[192], b4 = bp[256], b5 = bp[320];
        const f32x4 e4 = ee4p[t * 64 + l];
#pragma unroll
        for (int rt = 0; rt < 4; ++rt) {
            f32x4 acc = e4;
            acc = __builtin_amdgcn_mfma_f32_16x16x32_bf16(b0, xh[rt][0], acc, 0, 0, 0);
            acc = __builtin_amdgcn_mfma_f32_16x16x32_bf16(b1, xh[rt][1], acc, 0, 0, 0);
            acc = __builtin_amdgcn_mfma_f32_16x16x32_bf16(b2, xh[rt][0], acc, 0, 0, 0);
            acc = __builtin_amdgcn_mfma_f32_16x16x32_bf16(b3, xh[rt][1], acc, 0, 0, 0);
            acc = __builtin_amdgcn_mfma_f32_16x16x32_bf16(b4, xl[rt][0], acc, 0, 0, 0);
            acc = __builtin_amdgcn_mfma_f32_16x16x32_bf16(b5, xl[rt][1], acc, 0, 0, 0);
#pragma unroll
            for (int r = 0; r < 4; ++r) {
                const float v = acc[r];
                const int k = t * 16 + g * 4 + r;
                const bool c = v < best[rt];
                best2[rt] = c ? best[rt] : fminf(best2[rt], v);
                bestk[rt] = c ? k : bestk[rt];
                best[rt]  = c ? v : best[rt];
            }
        }
    }

#pragma unroll
    for (int rt = 0; rt < 4; ++rt) {
        float b = best[rt], b2 = best2[rt]; int k = bestk[rt];
#pragma unroll
        for (int sh = 16; sh <= 32; sh <<= 1) {    // merge the 4 g-groups
            const float ob  = __shfl_xor(b, sh, 64);
            const float ob2 = __shfl_xor(b2, sh, 64);
            const int   ok  = __shfl_xor(k, sh, 64);
            if (ob < b || (ob == b && ok < k)) { b2 = fminf(b, ob2); k = ok; b = ob; }
            else b2 = fminf(b2, ob);
        }
        if (g == 0) {
            const int row = rowBase + rt * 16 + col;
            pb[row * 4 + ks] = b; pb2[row * 4 + ks] = b2; pk[row * 4 + ks] = k;
        }
    }
}

// Merge the 4 K-split partials per row; write idx; flag small-gap rows.
__global__ __launch_bounds__(256) void k_merge(
        const float* __restrict__ pb, const float* __restrict__ pb2,
        const int* __restrict__ pk, int* __restrict__ idx,
        unsigned* __restrict__ flagcnt, unsigned* __restrict__ flaglist) {
    const int n = blockIdx.x * 256 + threadIdx.x;
    float b = pb[n * 4], b2 = pb2[n * 4]; int k = pk[n * 4];
#pragma unroll
    for (int s = 1; s < 4; ++s) {                   // ascending k ranges
        const float ob = pb[n * 4 + s], ob2 = pb2[n * 4 + s];
        const int ok = pk[n * 4 + s];
        if (ob < b || (ob == b && ok < k)) { b2 = fminf(b, ob2); k = ok; b = ob; }
        else b2 = fminf(b2, ob);
    }
    idx[n] = k;
    if (b2 - b < GAP1) {
        const unsigned p = atomicAdd(flagcnt, 1u);
        flaglist[p] = (unsigned)n;
    }
}

// fp64 exact argmin for flagged rows; one wave per row.
__global__ __launch_bounds__(256) void k_exact64(
        const float* __restrict__ in, const float* __restrict__ cb,
        const double* __restrict__ e2d, int* __restrict__ idx,
        const unsigned* __restrict__ flagcnt, const unsigned* __restrict__ flaglist) {
    const unsigned nf = *flagcnt;
    const int l = threadIdx.x & 63;
    const unsigned wave = blockIdx.x * 4u + (unsigned)(threadIdx.x >> 6);
    const unsigned nwave = gridDim.x * 4u;
    for (unsigned i = wave; i < nf; i += nwave) {
        const int row = (int)flaglist[i];
        float x[ED];
#pragma unroll
        for (int e = 0; e < ED; ++e) x[e] = in[(size_t)e * NR + row];
        double best = 1e300; int bestk = 0;
        for (int ci = 0; ci < 16; ++ci) {
            const int k = ci * 64 + l;              // ascending k per lane
            const float* c = cb + (size_t)k * ED;
            double s = 0.0;
            for (int e = 0; e < ED; ++e) s = fma((double)c[e], (double)x[e], s);
            const double t = fma(-2.0, s, e2d[k]);
            if (t < best) { best = t; bestk = k; }
        }
        for (int sh = 1; sh < 64; sh <<= 1) {
            const double ob = __shfl_xor(best, sh, 64);
            const int   ok  = __shfl_xor(bestk, sh, 64);
            if (ob < best || (ob == best && ok < bestk)) { best = ob; bestk = ok; }
        }
        if (l == 0) idx[row] = bestk;
    }
}

// Element-parallel gather/write/SSE + histogram. SSE: per-wave shfl reduce
// -> LDS -> one plain store per block (pblk[bid]); NO global atomics.
__global__ __launch_bounds__(256) void k_output(
        const float* __restrict__ in, const float* __restrict__ cb,
        const int* __restrict__ idx, float* __restrict__ qout,
        unsigned* __restrict__ counts, double* __restrict__ pblk) {
    __shared__ double sred[4];
    const int gtid = blockIdx.x * 256 + threadIdx.x;
    const int n = gtid & (NR - 1);
    const int e0 = gtid >> 16;                      // 0..7
    const int k = idx[n];
    if (e0 == 0) atomicAdd(&counts[k], 1u);
    const float4* c4 = (const float4*)(cb + (size_t)k * ED + e0 * 8);
    const float4 q0 = c4[0], q1 = c4[1];
    float local = 0.f;
#pragma unroll
    for (int j = 0; j < 8; ++j) {
        const int e = e0 * 8 + j;
        const float q = (j < 4) ? ((const float*)&q0)[j] : ((const float*)&q1)[j - 4];
        const float xv = in[(size_t)e * NR + n];
        qout[(size_t)e * NR + n] = q;
        const float d = q - xv;
        local = fmaf(d, d, local);
    }
    double ld = (double)local;
#pragma unroll
    for (int off = 32; off > 0; off >>= 1) ld += __shfl_down(ld, off, 64);
    if ((threadIdx.x & 63) == 0) sred[threadIdx.x >> 6] = ld;
    __syncthreads();
    if (threadIdx.x == 0)
        pblk[blockIdx.x] = (sred[0] + sred[1]) + (sred[2] + sred[3]);
}

// Final: entropy from counts + SSE from 2048 per-block partials (fixed-order
// tree -> deterministic).
__global__ __launch_bounds__(1024) void k_final(const unsigned* __restrict__ counts,
        const double* __restrict__ pblk, float* __restrict__ out) {
    __shared__ double redE[16], redS[16];
    const int tid = threadIdx.x;
    const double p = (double)counts[tid] * (1.0 / 65536.0);
    double term = p * log(p + 1e-10);
    double s = pblk[tid] + pblk[tid + 1024];
#pragma unroll
    for (int off = 32; off > 0; off >>= 1) {
        term += __shfl_down(term, off, 64);
        s    += __shfl_down(s,    off, 64);
    }
    if ((tid & 63) == 0) { redE[tid >> 6] = term; redS[tid >> 6] = s; }
    __syncthreads();
    if (tid == 0) {
        double e = 0.0, ss = 0.0;
        for (int i = 0; i < 16; ++i) { e += redE[i]; ss += redS[i]; }
        out[1 + NE] = (float)exp(-e);                 // perplexity
        const double m = ss * (1.0 / 4194304.0);      // mean((q-x)^2)
        out[0] = (float)(1.25 * m);                   // (1+beta)*m
    }
}

extern "C" void kernel_launch(void* const* d_in, const int* in_sizes, int n_in,
                              void* d_out, int out_size, void* d_ws, size_t ws_size,
                              hipStream_t stream) {
    (void)in_sizes; (void)n_in; (void)out_size; (void)ws_size;
    const float* in = (const float*)d_in[0];
    const float* cb = (const float*)d_in[1];
    float* out = (float*)d_out;

    // ws layout (dword offsets), strictly disjoint (lifetimes noted):
    //  [0,1024) counts | [1024] flagcnt | [1088,2112) ee | [2112,4160) e2d
    //  [4160,102464) cbp | [102464,118848) ee4p
    //  [118848,184384) idx | [184384,249920) flaglist
    //  [249920,512064) pb | [512064,774208) pb2 | [774208,1036352) pk
    //  pblk (2048 f64) OVERLAYS pb at dword 249920 (byte 999680, 8B-aligned):
    //  pb dead after k_merge; k_output writes pblk afterward (stream-ordered);
    //  both fully rewritten every call -> no cross-call state.
    unsigned* counts   = (unsigned*)d_ws;
    unsigned* flagcnt  = (unsigned*)d_ws + 1024;
    float*    ee       = (float*)d_ws + 1088;
    double*   e2d      = (double*)((char*)d_ws + 8448);
    short8*   cbp      = (short8*)((float*)d_ws + 4160);
    f32x4*    ee4p     = (f32x4*)((float*)d_ws + 102464);
    int*      idx      = (int*)d_ws + 118848;
    unsigned* flaglist = (unsigned*)d_ws + 184384;
    float*    pb       = (float*)d_ws + 249920;
    float*    pb2      = (float*)d_ws + 512064;
    int*      pk       = (int*)d_ws + 774208;
    double*   pblk     = (double*)((char*)d_ws + 999680);

    hipMemsetAsync(d_ws, 0, 4112, stream);  // counts + flagcnt

    hipLaunchKernelGGL(k_prep_ee,     dim3(4),    dim3(256), 0, stream, cb, ee, e2d);
    hipLaunchKernelGGL(k_pack,        dim3(112),  dim3(256), 0, stream, cb, ee, cbp, ee4p);
    hipLaunchKernelGGL(k_argmin_part, dim3(1024), dim3(256), 0, stream,
                       in, cbp, ee4p, pb, pb2, pk);
    hipLaunchKernelGGL(k_merge,       dim3(256),  dim3(256), 0, stream,
                       pb, pb2, pk, idx, flagcnt, flaglist);
    hipLaunchKernelGGL(k_exact64,     dim3(128),  dim3(256), 0, stream,
                       in, cb, e2d, idx, flagcnt, flaglist);
    hipLaunchKernelGGL(k_output,      dim3(2048), dim3(256), 0, stream,
                       in, cb, idx, out + 1, counts, pblk);
    hipLaunchKernelGGL(k_final,       dim3(1),    dim3(1024), 0, stream,
                       counts, pblk, out);
}

// Round 9
// 114.449 us; speedup vs baseline: 2.1505x; 1.0249x over previous
//
#include <hip/hip_runtime.h>

// VQ-VAE VectorQuantizer fwd. K=1024, E=64, N=T*B=65536.
// bf16-split MFMA argmin (gap<6e-6 flagged) -> fp64 exact re-resolve.
// Scores t = ||c||^2 - 2 x.c; codebook pre-scaled by -2, ||c||^2 in C-init.
// MFMA roles: A = codebook frag, B = x frag -> D(lane l, reg r) =
// score(code = t*16 + (l>>4)*4 + r, row = base + (l&15)).
// R9: K-split moved INSIDE the block. 1024 blocks x 8 waves; block owns 64
// rows, converts x->bf16 hi/lo ONCE into LDS (R8 redid it per K-split: 4x
// the VALU), each wave scans 8 code tiles, cross-wave top-2 merge in LDS.
// k_merge kernel and pb/pb2/pk buffers eliminated.

#define KC 1024
#define ED 64
#define NR 65536
#define NE (NR * ED)
#define GAP1 6e-6f

typedef __attribute__((ext_vector_type(8))) short short8;
typedef __attribute__((ext_vector_type(4))) float f32x4;

__device__ __forceinline__ unsigned short bf16rne(float f) {
    unsigned u = __builtin_bit_cast(unsigned, f);
    return (unsigned short)((u + 0x7fffu + ((u >> 16) & 1u)) >> 16);
}
__device__ __forceinline__ float bf16tof(unsigned short h) {
    return __builtin_bit_cast(float, (unsigned)h << 16);
}

// ee[k] = ||c_k||^2 (fp32) and e2d[k] (fp64)
__global__ __launch_bounds__(256) void k_prep_ee(const float* __restrict__ cb,
        float* __restrict__ ee, double* __restrict__ e2d) {
    int k = blockIdx.x * 256 + threadIdx.x;
    if (k >= KC) return;
    const float* c = cb + (size_t)k * ED;
    float s = 0.f; double sd = 0.0;
    for (int e = 0; e < ED; ++e) { float v = c[e]; s = fmaf(v, v, s); sd = fma((double)v, (double)v, sd); }
    ee[k] = s; e2d[k] = sd;
}

// Pack codebook fragments (MFMA A-operand): per code tile t, chunks j of
// -2*c: [ch e0-31|ch e32-63|cl e0-31|cl e32-63|ch e0-31|ch e32-63], paired
// at MFMA time with x chunks [xh0|xh1|xh0|xh1|xl0|xl1]. Element (g=l>>4,r)
// of a chunk <-> k-slot g*8+r (same bijection on both operands).
// cbp[(t*6+j)*64+l]; ee4p: reg r, lane l, tile t <-> code t*16+(l>>4)*4+r.
__global__ __launch_bounds__(256) void k_pack(const float* __restrict__ cb,
        const float* __restrict__ ee, short8* __restrict__ cbp,
        f32x4* __restrict__ ee4p) {
    int u = blockIdx.x * 256 + threadIdx.x;
    if (u < 64 * 6 * 64) {
        int t = u / 384, rem = u % 384, j = rem / 64, l = rem % 64;
        int code = t * 16 + (l & 15), g = l >> 4;
        const float* c = cb + (size_t)code * ED;
        short8 o;
#pragma unroll
        for (int r = 0; r < 8; ++r) {
            int k = j * 32 + g * 8 + r;
            int e; bool lo;
            if (j < 2)      { e = k;       lo = false; }
            else if (j < 4) { e = k - 64;  lo = true;  }
            else            { e = k - 128; lo = false; }
            float m2 = -2.f * c[e];
            unsigned short h = bf16rne(m2);
            o[r] = lo ? (short)bf16rne(m2 - bf16tof(h)) : (short)h;
        }
        cbp[u] = o;
    } else if (u < 64 * 6 * 64 + 64 * 64) {
        int v = u - 64 * 6 * 64;
        int t = v >> 6, l = v & 63, g = l >> 4;
        f32x4 o;
#pragma unroll
        for (int r = 0; r < 4; ++r) o[r] = ee[t * 16 + g * 4 + r];
        ee4p[v] = o;
    }
}

// 1024 blocks x 512 threads (8 waves). Block owns rows [bid*64, bid*64+64).
// Phase 1: 512 threads convert the block's x to bf16 hi/lo short8 frags in
// LDS (once). Phase 2: wave w scans code tiles [w*8, w*8+8), x frags from
// LDS, b stream from global. Phase 3: intra-wave shfl merge over g-groups,
// cross-wave LDS merge (ascending w == ascending k -> first-min tie-break).
__global__ __launch_bounds__(512) void k_argmin(
        const float* __restrict__ in, const short8* __restrict__ cbp,
        const f32x4* __restrict__ ee4p, int* __restrict__ idx,
        unsigned* __restrict__ flagcnt, unsigned* __restrict__ flaglist) {
    __shared__ short8 xs[16][64];                 // [rt*4+q][l], 16KB
    __shared__ float sb[8][4][16], sb2[8][4][16];
    __shared__ int   sk[8][4][16];

    const int tid = threadIdx.x;
    const int l = tid & 63;
    const int wid = tid >> 6;                     // 0..7
    const int g = l >> 4;
    const int col = l & 15;
    const int rowBase = blockIdx.x * 64;

    // Phase 1: thread (row=tid&63, oct=tid>>6) builds the hi and lo short8
    // for lane ll=(oct&3)*16+(row&15), q=(oct>>2) and q+2, rowtile row>>4.
    {
        const int row = tid & 63;
        const int oct = tid >> 6;                 // 0..7
        const int h = oct >> 2;                   // 0..1
        const int ll = (oct & 3) * 16 + (row & 15);
        const int rt = row >> 4;
        short8 H, L;
#pragma unroll
        for (int j = 0; j < 8; ++j) {             // e = oct*8+j = h*32+g*8+j
            const float x = in[(size_t)(oct * 8 + j) * NR + rowBase + row];
            const unsigned short hb = bf16rne(x);
            H[j] = (short)hb;
            L[j] = (short)bf16rne(x - bf16tof(hb));
        }
        xs[rt * 4 + h][ll] = H;
        xs[rt * 4 + 2 + h][ll] = L;
    }
    __syncthreads();

    // Phase 2: stage this lane's fragments from LDS, scan 8 tiles.
    short8 xq[4][4];
#pragma unroll
    for (int rt = 0; rt < 4; ++rt)
#pragma unroll
        for (int q = 0; q < 4; ++q)
            xq[rt][q] = xs[rt * 4 + q][l];

    float best[4]  = {3.4e38f, 3.4e38f, 3.4e38f, 3.4e38f};
    float best2[4] = {3.4e38f, 3.4e38f, 3.4e38f, 3.4e38f};
    int bestk[4] = {0, 0, 0, 0};

    const int t0 = wid * 8;
#pragma unroll 2
    for (int tt = 0; tt < 8; ++tt) {
        const int t = t0 + tt;
        const short8* bp = cbp + t * 384 + l;
        const short8 b0 = bp[0], b1 = bp[64], b2 = bp[128],
                     b3 = bp[192], b4 = bp[256], b5 = bp[320];
        const f32x4 e4 = ee4p[t * 64 + l];
#pragma unroll
        for (int rt = 0; rt < 4; ++rt) {
            f32x4 acc = e4;
            acc = __builtin_amdgcn_mfma_f32_16x16x32_bf16(b0, xq[rt][0], acc, 0, 0, 0);
            acc = __builtin_amdgcn_mfma_f32_16x16x32_bf16(b1, xq[rt][1], acc, 0, 0, 0);
            acc = __builtin_amdgcn_mfma_f32_16x16x32_bf16(b2, xq[rt][0], acc, 0, 0, 0);
            acc = __builtin_amdgcn_mfma_f32_16x16x32_bf16(b3, xq[rt][1], acc, 0, 0, 0);
            acc = __builtin_amdgcn_mfma_f32_16x16x32_bf16(b4, xq[rt][2], acc, 0, 0, 0);
            acc = __builtin_amdgcn_mfma_f32_16x16x32_bf16(b5, xq[rt][3], acc, 0, 0, 0);
#pragma unroll
            for (int r = 0; r < 4; ++r) {
                const float v = acc[r];
                const int k = t * 16 + g * 4 + r;
                const bool c = v < best[rt];
                best2[rt] = c ? best[rt] : fminf(best2[rt], v);
                bestk[rt] = c ? k : bestk[rt];
                best[rt]  = c ? v : best[rt];
            }
        }
    }

    // Phase 3a: intra-wave merge over the 4 g-groups.
#pragma unroll
    for (int rt = 0; rt < 4; ++rt) {
        float b = best[rt], b2 = best2[rt]; int k = bestk[rt];
#pragma unroll
        for (int sh = 16; sh <= 32; sh <<= 1) {
            const float ob  = __shfl_xor(b, sh, 64);
            const float ob2 = __shfl_xor(b2, sh, 64);
            const int   ok  = __shfl_xor(k, sh, 64);
            if (ob < b || (ob == b && ok < k)) { b2 = fminf(b, ob2); k = ok; b = ob; }
            else b2 = fminf(b2, ob);
        }
        if (g == 0) { sb[wid][rt][col] = b; sb2[wid][rt][col] = b2; sk[wid][rt][col] = k; }
    }
    __syncthreads();

    // Phase 3b: wave 0 merges the 8 wave-partials (ascending w == asc k).
    if (wid == 0) {
        const int rt = l >> 4, c2 = l & 15;
        float b = sb[0][rt][c2], b2 = sb2[0][rt][c2]; int k = sk[0][rt][c2];
#pragma unroll
        for (int w = 1; w < 8; ++w) {
            const float ob = sb[w][rt][c2], ob2 = sb2[w][rt][c2];
            const int ok = sk[w][rt][c2];
            if (ob < b || (ob == b && ok < k)) { b2 = fminf(b, ob2); k = ok; b = ob; }
            else b2 = fminf(b2, ob);
        }
        const int row = rowBase + rt * 16 + c2;
        idx[row] = k;
        if (b2 - b < GAP1) {
            const unsigned p = atomicAdd(flagcnt, 1u);
            flaglist[p] = (unsigned)row;
        }
    }
}

// fp64 exact argmin for flagged rows; one wave per row.
__global__ __launch_bounds__(256) void k_exact64(
        const float* __restrict__ in, const float* __restrict__ cb,
        const double* __restrict__ e2d, int* __restrict__ idx,
        const unsigned* __restrict__ flagcnt, const unsigned* __restrict__ flaglist) {
    const unsigned nf = *flagcnt;
    const int l = threadIdx.x & 63;
    const unsigned wave = blockIdx.x * 4u + (unsigned)(threadIdx.x >> 6);
    const unsigned nwave = gridDim.x * 4u;
    for (unsigned i = wave; i < nf; i += nwave) {
        const int row = (int)flaglist[i];
        float x[ED];
#pragma unroll
        for (int e = 0; e < ED; ++e) x[e] = in[(size_t)e * NR + row];
        double best = 1e300; int bestk = 0;
        for (int ci = 0; ci < 16; ++ci) {
            const int k = ci * 64 + l;              // ascending k per lane
            const float* c = cb + (size_t)k * ED;
            double s = 0.0;
            for (int e = 0; e < ED; ++e) s = fma((double)c[e], (double)x[e], s);
            const double t = fma(-2.0, s, e2d[k]);
            if (t < best) { best = t; bestk = k; }
        }
        for (int sh = 1; sh < 64; sh <<= 1) {
            const double ob = __shfl_xor(best, sh, 64);
            const int   ok  = __shfl_xor(bestk, sh, 64);
            if (ob < best || (ob == best && ok < bestk)) { best = ob; bestk = ok; }
        }
        if (l == 0) idx[row] = bestk;
    }
}

// Element-parallel gather/write/SSE + histogram. SSE: per-wave shfl reduce
// -> LDS -> one plain store per block (pblk[bid]); NO global atomics.
__global__ __launch_bounds__(256) void k_output(
        const float* __restrict__ in, const float* __restrict__ cb,
        const int* __restrict__ idx, float* __restrict__ qout,
        unsigned* __restrict__ counts, double* __restrict__ pblk) {
    __shared__ double sred[4];
    const int gtid = blockIdx.x * 256 + threadIdx.x;
    const int n = gtid & (NR - 1);
    const int e0 = gtid >> 16;                      // 0..7
    const int k = idx[n];
    if (e0 == 0) atomicAdd(&counts[k], 1u);
    const float4* c4 = (const float4*)(cb + (size_t)k * ED + e0 * 8);
    const float4 q0 = c4[0], q1 = c4[1];
    float local = 0.f;
#pragma unroll
    for (int j = 0; j < 8; ++j) {
        const int e = e0 * 8 + j;
        const float q = (j < 4) ? ((const float*)&q0)[j] : ((const float*)&q1)[j - 4];
        const float xv = in[(size_t)e * NR + n];
        qout[(size_t)e * NR + n] = q;
        const float d = q - xv;
        local = fmaf(d, d, local);
    }
    double ld = (double)local;
#pragma unroll
    for (int off = 32; off > 0; off >>= 1) ld += __shfl_down(ld, off, 64);
    if ((threadIdx.x & 63) == 0) sred[threadIdx.x >> 6] = ld;
    __syncthreads();
    if (threadIdx.x == 0)
        pblk[blockIdx.x] = (sred[0] + sred[1]) + (sred[2] + sred[3]);
}

// Final: entropy from counts + SSE from 2048 per-block partials (fixed-order
// tree -> deterministic).
__global__ __launch_bounds__(1024) void k_final(const unsigned* __restrict__ counts,
        const double* __restrict__ pblk, float* __restrict__ out) {
    __shared__ double redE[16], redS[16];
    const int tid = threadIdx.x;
    const double p = (double)counts[tid] * (1.0 / 65536.0);
    double term = p * log(p + 1e-10);
    double s = pblk[tid] + pblk[tid + 1024];
#pragma unroll
    for (int off = 32; off > 0; off >>= 1) {
        term += __shfl_down(term, off, 64);
        s    += __shfl_down(s,    off, 64);
    }
    if ((tid & 63) == 0) { redE[tid >> 6] = term; redS[tid >> 6] = s; }
    __syncthreads();
    if (tid == 0) {
        double e = 0.0, ss = 0.0;
        for (int i = 0; i < 16; ++i) { e += redE[i]; ss += redS[i]; }
        out[1 + NE] = (float)exp(-e);                 // perplexity
        const double m = ss * (1.0 / 4194304.0);      // mean((q-x)^2)
        out[0] = (float)(1.25 * m);                   // (1+beta)*m
    }
}

extern "C" void kernel_launch(void* const* d_in, const int* in_sizes, int n_in,
                              void* d_out, int out_size, void* d_ws, size_t ws_size,
                              hipStream_t stream) {
    (void)in_sizes; (void)n_in; (void)out_size; (void)ws_size;
    const float* in = (const float*)d_in[0];
    const float* cb = (const float*)d_in[1];
    float* out = (float*)d_out;

    // ws layout (dword offsets), strictly disjoint:
    //  [0,1024) counts | [1024] flagcnt | [1088,2112) ee | [2112,4160) e2d
    //  [4160,102464) cbp 24576 short8 | [102464,118848) ee4p 4096 f32x4
    //  [118848,184384) idx | [184384,249920) flaglist
    //  pblk (2048 f64) at byte 999680 (8B-aligned, formerly pb region)
    unsigned* counts   = (unsigned*)d_ws;
    unsigned* flagcnt  = (unsigned*)d_ws + 1024;
    float*    ee       = (float*)d_ws + 1088;
    double*   e2d      = (double*)((char*)d_ws + 8448);
    short8*   cbp      = (short8*)((float*)d_ws + 4160);
    f32x4*    ee4p     = (f32x4*)((float*)d_ws + 102464);
    int*      idx      = (int*)d_ws + 118848;
    unsigned* flaglist = (unsigned*)d_ws + 184384;
    double*   pblk     = (double*)((char*)d_ws + 999680);

    hipMemsetAsync(d_ws, 0, 4112, stream);  // counts + flagcnt

    hipLaunchKernelGGL(k_prep_ee, dim3(4),    dim3(256),  0, stream, cb, ee, e2d);
    hipLaunchKernelGGL(k_pack,    dim3(112),  dim3(256),  0, stream, cb, ee, cbp, ee4p);
    hipLaunchKernelGGL(k_argmin,  dim3(1024), dim3(512),  0, stream,
                       in, cbp, ee4p, idx, flagcnt, flaglist);
    hipLaunchKernelGGL(k_exact64, dim3(128),  dim3(256),  0, stream,
                       in, cb, e2d, idx, flagcnt, flaglist);
    hipLaunchKernelGGL(k_output,  dim3(2048), dim3(256),  0, stream,
                       in, cb, idx, out + 1, counts, pblk);
    hipLaunchKernelGGL(k_final,   dim3(1),    dim3(1024), 0, stream,
                       counts, pblk, out);
}